// Round 6
// baseline (390.338 us; speedup 1.0000x reference)
//
#include <hip/hip_runtime.h>
#include <hip/hip_bf16.h>

typedef __bf16 bf16;
typedef __bf16 bf16x4 __attribute__((ext_vector_type(4)));
typedef __bf16 bf16x8 __attribute__((ext_vector_type(8)));
typedef float  f32x4  __attribute__((ext_vector_type(4)));

#define SEQ  2048
#define HID  4096
#define QKVN 6144   // 4096 Q + 1024 K + 1024 V

__device__ __forceinline__ void gload_lds16(const void* g, void* l) {
  __builtin_amdgcn_global_load_lds(
      (const __attribute__((address_space(1))) void*)g,
      (__attribute__((address_space(3))) void*)l, 16, 0, 0);
}

// ---------------- cast f32 -> bf16 (vectorized) ----------------
__global__ __launch_bounds__(256) void cast_f32_bf16(const float* __restrict__ in,
                                                     bf16* __restrict__ out, int n) {
  int i = (blockIdx.x * 256 + threadIdx.x) * 4;
  int stride = gridDim.x * 256 * 4;
  for (; i < n; i += stride) {
    float4 v = *(const float4*)(in + i);
    bf16x4 o;
    o[0] = (bf16)v.x; o[1] = (bf16)v.y; o[2] = (bf16)v.z; o[3] = (bf16)v.w;
    *(bf16x4*)(out + i) = o;
  }
}

// ---------------- tiled transpose + cast: W[4096][N] f32 -> Wt[roff+N][4096] bf16 ----------------
__global__ __launch_bounds__(256) void transpose_cast(const float* __restrict__ W,
                                                      bf16* __restrict__ Wt,
                                                      int N, int roff) {
  __shared__ float tile[32][33];
  int k0 = blockIdx.y * 32;
  int n0 = blockIdx.x * 32;
  int t = threadIdx.x;
  int r = t >> 5, c = t & 31;
#pragma unroll
  for (int p = 0; p < 4; ++p)
    tile[r + p * 8][c] = W[(size_t)(k0 + r + p * 8) * N + n0 + c];
  __syncthreads();
#pragma unroll
  for (int p = 0; p < 4; ++p)
    Wt[(size_t)(roff + n0 + r + p * 8) * 4096 + k0 + c] = (bf16)tile[c][r + p * 8];
}

// ---------------- transpose V out of QKV into global: Vt_g[g][d][s] ----------------
__global__ __launch_bounds__(256) void transpose_v(const bf16* __restrict__ QKV,
                                                   bf16* __restrict__ Vt_g) {
  __shared__ bf16 tile[32][33];
  int s0 = blockIdx.x * 32;          // seq tile
  int d0 = blockIdx.y * 32;          // head-dim tile
  int g  = blockIdx.z;               // kv head
  int t = threadIdx.x;
  int r = t >> 5, c = t & 31;
#pragma unroll
  for (int p = 0; p < 4; ++p)
    tile[r + p * 8][c] = QKV[(size_t)(s0 + r + p * 8) * QKVN + 5120 + g * 128 + d0 + c];
  __syncthreads();
#pragma unroll
  for (int p = 0; p < 4; ++p)
    Vt_g[(size_t)(g * 128 + d0 + r + p * 8) * SEQ + s0 + c] = tile[c][r + p * 8];
}

// ---------------- 128x128 GEMM, BK=64, swizzled LDS: A[M,K] @ Bt[N,K]^T -> C[M,ldc] ----------------
template <typename OUT_T>
__global__ __launch_bounds__(256) void gemm_bt(const bf16* __restrict__ A,
                                               const bf16* __restrict__ Bt,
                                               OUT_T* __restrict__ C,
                                               int K, int ldc) {
  __shared__ __align__(16) bf16 Abuf[128 * 64];
  __shared__ __align__(16) bf16 Bbuf[128 * 64];
  int m0 = blockIdx.y * 128, n0 = blockIdx.x * 128;
  int tid = threadIdx.x, w = tid >> 6, lane = tid & 63;
  int wr = w >> 1, wc = w & 1;
  int l15 = lane & 15, l4 = lane >> 4;
  f32x4 acc[4][4] = {};
  const int nk = K >> 6;
  for (int kt = 0; kt < nk; ++kt) {
    int k0 = kt << 6;
#pragma unroll
    for (int p = 0; p < 4; ++p) {
      int c = p * 256 + tid;
      int row = c >> 3, slot = c & 7;
      int ssl = (slot ^ (row & 7)) << 4;   // inverse-swizzled source byte offset
      gload_lds16((const char*)(A + (size_t)(m0 + row) * K + k0) + ssl, (char*)Abuf + c * 16);
      gload_lds16((const char*)(Bt + (size_t)(n0 + row) * K + k0) + ssl, (char*)Bbuf + c * 16);
    }
    __syncthreads();
    bf16x8 af[4][2], bfr[4][2];
#pragma unroll
    for (int m = 0; m < 4; ++m)
#pragma unroll
      for (int kk = 0; kk < 2; ++kk) {
        int row = wr * 64 + m * 16 + l15;
        af[m][kk] = *(const bf16x8*)((const char*)Abuf + row * 128 +
                                     (((kk * 4 + l4) ^ (row & 7)) << 4));
      }
#pragma unroll
    for (int n = 0; n < 4; ++n)
#pragma unroll
      for (int kk = 0; kk < 2; ++kk) {
        int row = wc * 64 + n * 16 + l15;
        bfr[n][kk] = *(const bf16x8*)((const char*)Bbuf + row * 128 +
                                      (((kk * 4 + l4) ^ (row & 7)) << 4));
      }
#pragma unroll
    for (int kk = 0; kk < 2; ++kk)
#pragma unroll
      for (int m = 0; m < 4; ++m)
#pragma unroll
        for (int n = 0; n < 4; ++n)
          acc[m][n] = __builtin_amdgcn_mfma_f32_16x16x32_bf16(af[m][kk], bfr[n][kk],
                                                              acc[m][n], 0, 0, 0);
    __syncthreads();
  }
#pragma unroll
  for (int m = 0; m < 4; ++m)
#pragma unroll
    for (int n = 0; n < 4; ++n)
#pragma unroll
      for (int i = 0; i < 4; ++i) {
        int row = m0 + wr * 64 + m * 16 + l4 * 4 + i;
        int col = n0 + wc * 64 + n * 16 + l15;
        C[(size_t)row * ldc + col] = (OUT_T)acc[m][n][i];
      }
}

// ---------------- flash-style causal GQA attention, v4 ----------------
// 256 blocks x 512 thr. Block = kv-head g (bid&7, XCD) x head-pair hg x qb-pair
// (qb_a = pair, qb_b = 31-pair: exactly 33 compute-units, 32-pair staged tiles).
// v4: merged A/B tile pass — each K/V fragment read from LDS ONCE and fed to both
// q-blocks' MFMAs (A guarded by uniform doA); A/B softmax chains independent ->
// VALU overlaps MFMA issue. launch_bounds(512,1): VGPR free to ~200 (no spill);
// LDS 80KB. K/V double-buffered, stage(t+1) issued before compute(t).
__global__ __launch_bounds__(512, 1) void attn_kernel(const bf16* __restrict__ QKV,
                                                      const bf16* __restrict__ Vt_g,
                                                      bf16* __restrict__ attn) {
  __shared__ __align__(16) bf16 Klds[2][64 * 128];   // [ks][d], XOR-swizzled
  __shared__ __align__(16) bf16 Vlds[2][64 * 128];   // [d][ks], XOR-swizzled
  __shared__ __align__(16) bf16 Plds[8 * 16 * 64];   // per-wave [16 q][64 ks], swizzled
  const int bid = blockIdx.x;
  const int g = bid & 7;                 // kv head -> XCD
  const int rest = bid >> 3;             // 0..31
  const int hg = rest & 1;               // head pair within kv group
  const int pair = rest >> 1;            // 0..15
  const int qb_a = pair, qb_b = 31 - pair;
  const int tid = threadIdx.x, w = tid >> 6, lane = tid & 63;
  const int hsel = w >> 2, qw = w & 3;
  const int h = g * 4 + hg * 2 + hsel;   // this wave's q head
  const int l15 = lane & 15, l4 = lane >> 4;
  const int wqA = qb_a * 64 + qw * 16;   // wave's q-row base, block A
  const int wqB = qb_b * 64 + qw * 16;   // block B
  const int qcol = h * 128;
  const int kcol = 4096 + g * 128;
  const float scale = 0.08838834764831845f;  // 1/sqrt(128)
  const float LOG2E = 1.4426950408889634f;

  const bf16* Vhead = Vt_g + (size_t)g * 128 * SEQ;

  // hoist Q fragments for both q-blocks (16 rows x 128 d each)
  bf16x8 aqA[4], aqB[4];
#pragma unroll
  for (int kc = 0; kc < 4; ++kc) {
    aqA[kc] = *(const bf16x8*)(QKV + (size_t)(wqA + l15) * QKVN + qcol + kc * 32 + l4 * 8);
    aqB[kc] = *(const bf16x8*)(QKV + (size_t)(wqB + l15) * QKVN + qcol + kc * 32 + l4 * 8);
  }

  f32x4 acc_oA[8] = {}, acc_oB[8] = {};
  float mA[4], lA[4], mB[4], lB[4];
#pragma unroll
  for (int i = 0; i < 4; ++i) { mA[i] = -1e30f; lA[i] = 0.f; mB[i] = -1e30f; lB[i] = 0.f; }

  // stage K/V tile at k-offset kb into buffer buf (1024 16B-chunks each, 512 thr x 2)
  auto stageKV = [&](int kb, int buf) {
#pragma unroll
    for (int j = 0; j < 2; ++j) {
      int c = tid + (j << 9);
      int krow = c >> 4, kslot = c & 15;
      gload_lds16((const char*)(QKV + (size_t)(kb + krow) * QKVN + kcol) +
                      ((kslot ^ (krow & 7)) << 4),
                  (char*)Klds[buf] + c * 16);
      int vrow = c >> 3, vslot = c & 7;
      gload_lds16(Vhead + (size_t)vrow * SEQ + kb + ((vslot ^ (vrow & 7)) << 3),
                  (char*)Vlds[buf] + c * 16);
    }
  };

  // softmax + P-write + P-frag read for one (head,q-block) unit. Uses per-wave P region
  // (reused A then B; DS ops are in-order per wave, fences keep compiler order).
  auto softmax_and_P = [&](f32x4* accs, float* mrow, float* lrow, f32x4* acc_o,
                           int wq0, int kb, bf16x8* pa) {
    bool needmask = (kb + 64 > wq0);
    float s[4][4];
#pragma unroll
    for (int n = 0; n < 4; ++n)
#pragma unroll
      for (int i = 0; i < 4; ++i) {
        float v = accs[n][i] * scale;
        if (needmask) {
          int ks = kb + n * 16 + l15;
          int qr = wq0 + l4 * 4 + i;
          if (ks > qr) v = -1e30f;
        }
        s[n][i] = v;
      }
    float t4[4];
#pragma unroll
    for (int i = 0; i < 4; ++i) {
      float t = fmaxf(fmaxf(s[0][i], s[1][i]), fmaxf(s[2][i], s[3][i]));
      t = fmaxf(t, __shfl_xor(t, 1));
      t = fmaxf(t, __shfl_xor(t, 2));
      t = fmaxf(t, __shfl_xor(t, 4));
      t = fmaxf(t, __shfl_xor(t, 8));
      t4[i] = t;
    }
    float dm = fmaxf(fmaxf(t4[0] - mrow[0], t4[1] - mrow[1]),
                     fmaxf(t4[2] - mrow[2], t4[3] - mrow[3]));
    if (!__all(dm <= 8.0f)) {      // T13 defer-max
      float fac[4];
#pragma unroll
      for (int i = 0; i < 4; ++i) {
        float mnew = fmaxf(mrow[i], t4[i]);
        fac[i] = exp2f((mrow[i] - mnew) * LOG2E);
        mrow[i] = mnew;
        lrow[i] *= fac[i];
      }
#pragma unroll
      for (int n2 = 0; n2 < 8; ++n2)
#pragma unroll
        for (int i = 0; i < 4; ++i)
          acc_o[n2][i] *= fac[i];
    }
    float ps[4][4];
#pragma unroll
    for (int i = 0; i < 4; ++i) {
      float psum = 0.f;
#pragma unroll
      for (int n = 0; n < 4; ++n) {
        float p = exp2f((s[n][i] - mrow[i]) * LOG2E);
        ps[n][i] = p; psum += p;
      }
      psum += __shfl_xor(psum, 1);
      psum += __shfl_xor(psum, 2);
      psum += __shfl_xor(psum, 4);
      psum += __shfl_xor(psum, 8);
      lrow[i] += psum;
    }
    char* Pw = (char*)Plds + w * 2048;
#pragma unroll
    for (int n = 0; n < 4; ++n)
#pragma unroll
      for (int i = 0; i < 4; ++i) {
        int r = l4 * 4 + i;
        int b = (r * 128 + (n * 16 + l15) * 2) ^ ((r & 7) << 4);
        *(bf16*)(Pw + b) = (bf16)ps[n][i];
      }
    __builtin_amdgcn_sched_barrier(0);
    asm volatile("" ::: "memory");
#pragma unroll
    for (int kc = 0; kc < 2; ++kc)
      pa[kc] = *(const bf16x8*)(Pw + (l15 * 128 + ((kc * 64 + l4 * 16) ^ ((l15 & 7) << 4))));
    __builtin_amdgcn_sched_barrier(0);
    asm volatile("" ::: "memory");   // keep later P-writes after these reads
  };

  // merged per-tile pass: shared bk/bv reads feed both q-blocks
  auto compute_tile = [&](int kb, int cur, bool doA) {
    const char* Kbuf = (const char*)Klds[cur];
    const char* Vbuf = (const char*)Vlds[cur];
    f32x4 accsA[4] = {}, accsB[4] = {};
    __builtin_amdgcn_s_setprio(1);
    if (doA) {
#pragma unroll
      for (int n = 0; n < 4; ++n) {
        int row_ = n * 16 + l15;
        int sw = (row_ & 7) << 4;
#pragma unroll
        for (int kc = 0; kc < 4; ++kc) {
          bf16x8 bk = *(const bf16x8*)(Kbuf + row_ * 256 + ((kc * 64 + l4 * 16) ^ sw));
          accsA[n] = __builtin_amdgcn_mfma_f32_16x16x32_bf16(aqA[kc], bk, accsA[n], 0, 0, 0);
          accsB[n] = __builtin_amdgcn_mfma_f32_16x16x32_bf16(aqB[kc], bk, accsB[n], 0, 0, 0);
        }
      }
    } else {
#pragma unroll
      for (int n = 0; n < 4; ++n) {
        int row_ = n * 16 + l15;
        int sw = (row_ & 7) << 4;
#pragma unroll
        for (int kc = 0; kc < 4; ++kc) {
          bf16x8 bk = *(const bf16x8*)(Kbuf + row_ * 256 + ((kc * 64 + l4 * 16) ^ sw));
          accsB[n] = __builtin_amdgcn_mfma_f32_16x16x32_bf16(aqB[kc], bk, accsB[n], 0, 0, 0);
        }
      }
    }
    __builtin_amdgcn_s_setprio(0);
    bf16x8 paA[2], paB[2];
    if (doA) softmax_and_P(accsA, mA, lA, acc_oA, wqA, kb, paA);
    softmax_and_P(accsB, mB, lB, acc_oB, wqB, kb, paB);
    __builtin_amdgcn_s_setprio(1);
    if (doA) {
#pragma unroll
      for (int n2 = 0; n2 < 8; ++n2) {
        int row_ = n2 * 16 + l15;
        int sw = (row_ & 7) << 4;
#pragma unroll
        for (int kc = 0; kc < 2; ++kc) {
          bf16x8 bv = *(const bf16x8*)(Vbuf + row_ * 128 + ((kc * 64 + l4 * 16) ^ sw));
          acc_oA[n2] = __builtin_amdgcn_mfma_f32_16x16x32_bf16(paA[kc], bv, acc_oA[n2], 0, 0, 0);
          acc_oB[n2] = __builtin_amdgcn_mfma_f32_16x16x32_bf16(paB[kc], bv, acc_oB[n2], 0, 0, 0);
        }
      }
    } else {
#pragma unroll
      for (int n2 = 0; n2 < 8; ++n2) {
        int row_ = n2 * 16 + l15;
        int sw = (row_ & 7) << 4;
#pragma unroll
        for (int kc = 0; kc < 2; ++kc) {
          bf16x8 bv = *(const bf16x8*)(Vbuf + row_ * 128 + ((kc * 64 + l4 * 16) ^ sw));
          acc_oB[n2] = __builtin_amdgcn_mfma_f32_16x16x32_bf16(paB[kc], bv, acc_oB[n2], 0, 0, 0);
        }
      }
    }
    __builtin_amdgcn_s_setprio(0);
    asm volatile("" ::: "memory");
  };

  // ---- prologue: stage tile 0; drain ----
  stageKV(0, 0);
  __syncthreads();

  int cur = 0;
  for (int kbi = 0; kbi <= qb_b; ++kbi) {
    int kb = kbi * 64;
    if (kbi < qb_b) stageKV(kb + 64, cur ^ 1);        // issue-early (overlaps compute)
    compute_tile(kb, cur, kbi <= qb_a);
    __syncthreads();                                   // vmcnt(0)+barrier per tile
    cur ^= 1;
  }

  // ---- epilogue ----
#pragma unroll
  for (int n2 = 0; n2 < 8; ++n2)
#pragma unroll
    for (int i = 0; i < 4; ++i) {
      int col = qcol + n2 * 16 + l15;
      attn[(size_t)(wqA + l4 * 4 + i) * 4096 + col] = (bf16)(acc_oA[n2][i] / lA[i]);
      attn[(size_t)(wqB + l4 * 4 + i) * 4096 + col] = (bf16)(acc_oB[n2][i] / lB[i]);
    }
}

extern "C" void kernel_launch(void* const* d_in, const int* in_sizes, int n_in,
                              void* d_out, int out_size, void* d_ws, size_t ws_size,
                              hipStream_t stream) {
  const float* X  = (const float*)d_in[0];
  const float* Wq = (const float*)d_in[1];
  const float* Wk = (const float*)d_in[2];
  const float* Wv = (const float*)d_in[3];
  const float* Wo = (const float*)d_in[4];
  float* out = (float*)d_out;

  const size_t XB_OFF  = 0;
  const size_t WT_OFF  = 16777216;
  const size_t VT_OFF  = WT_OFF + 33554432;       // inside Wt region, past Wo^T
  const size_t QKV_OFF = 16777216 + 50331648;
  if (ws_size < (size_t)92274688) return;

  char* ws = (char*)d_ws;
  bf16* Xb    = (bf16*)(ws + XB_OFF);
  bf16* Wt    = (bf16*)(ws + WT_OFF);
  bf16* Vt_g  = (bf16*)(ws + VT_OFF);
  bf16* QKV   = (bf16*)(ws + QKV_OFF);
  bf16* attnb = Xb;  // reuse after gemm1 consumed Xb

  // 1. cast hidden states
  cast_f32_bf16<<<2048, 256, 0, stream>>>(X, Xb, SEQ * HID);
  // 2. transpose-cast Wq/Wk/Wv into fused [6144][4096] B^T
  transpose_cast<<<dim3(4096 / 32, 4096 / 32), 256, 0, stream>>>(Wq, Wt, 4096, 0);
  transpose_cast<<<dim3(1024 / 32, 4096 / 32), 256, 0, stream>>>(Wk, Wt, 1024, 4096);
  transpose_cast<<<dim3(1024 / 32, 4096 / 32), 256, 0, stream>>>(Wv, Wt, 1024, 5120);
  // 3. fused QKV projection: [2048,4096] @ [4096,6144]
  gemm_bt<bf16><<<dim3(QKVN / 128, SEQ / 128), 256, 0, stream>>>(Xb, Wt, QKV, HID, QKVN);
  // 4. transpose-cast Wo (reuses Wt space) + transpose V into global [g][d][s]
  transpose_cast<<<dim3(4096 / 32, 4096 / 32), 256, 0, stream>>>(Wo, Wt, 4096, 0);
  transpose_v<<<dim3(SEQ / 32, 4, 8), 256, 0, stream>>>(QKV, Vt_g);
  // 5. causal GQA flash attention v4 (merged A/B shared-fragment pass)
  attn_kernel<<<256, 512, 0, stream>>>(QKV, Vt_g, attnb);
  // 6. output projection -> f32 out: [2048,4096] @ [4096,4096]
  gemm_bt<float><<<dim3(4096 / 128, SEQ / 128), 256, 0, stream>>>(attnb, Wt, out, HID, 4096);
}

// Round 7
// 379.757 us; speedup vs baseline: 1.0279x; 1.0279x over previous
//
#include <hip/hip_runtime.h>
#include <hip/hip_bf16.h>

typedef __bf16 bf16;
typedef __bf16 bf16x4 __attribute__((ext_vector_type(4)));
typedef __bf16 bf16x8 __attribute__((ext_vector_type(8)));
typedef float  f32x4  __attribute__((ext_vector_type(4)));

#define SEQ  2048
#define HID  4096
#define QKVN 6144   // 4096 Q + 1024 K + 1024 V

__device__ __forceinline__ void gload_lds16(const void* g, void* l) {
  __builtin_amdgcn_global_load_lds(
      (const __attribute__((address_space(1))) void*)g,
      (__attribute__((address_space(3))) void*)l, 16, 0, 0);
}

// ---------------- cast f32 -> bf16 (vectorized) ----------------
__global__ __launch_bounds__(256) void cast_f32_bf16(const float* __restrict__ in,
                                                     bf16* __restrict__ out, int n) {
  int i = (blockIdx.x * 256 + threadIdx.x) * 4;
  int stride = gridDim.x * 256 * 4;
  for (; i < n; i += stride) {
    float4 v = *(const float4*)(in + i);
    bf16x4 o;
    o[0] = (bf16)v.x; o[1] = (bf16)v.y; o[2] = (bf16)v.z; o[3] = (bf16)v.w;
    *(bf16x4*)(out + i) = o;
  }
}

// ---------------- tiled transpose + cast: W[4096][N] f32 -> Wt[roff+N][4096] bf16 ----------------
// 64x64 tile, float4 global loads (16B/lane), bf16x4 stores (8B/lane), [64][65] pad:
// both LDS phases verified 2-way bank aliasing (free).
__global__ __launch_bounds__(256) void transpose_cast(const float* __restrict__ W,
                                                      bf16* __restrict__ Wt,
                                                      int N, int roff) {
  __shared__ float tile[64][65];
  int k0 = blockIdx.y * 64;   // row block in W (K dim)
  int n0 = blockIdx.x * 64;   // col block in W (N dim)
  int t = threadIdx.x;
  int lr = t >> 4;            // 0..15
  int lc = (t & 15) * 4;      // 0,4,...,60
#pragma unroll
  for (int p = 0; p < 4; ++p) {
    int row = p * 16 + lr;
    float4 v = *(const float4*)(W + (size_t)(k0 + row) * N + n0 + lc);
    tile[row][lc] = v.x; tile[row][lc + 1] = v.y;
    tile[row][lc + 2] = v.z; tile[row][lc + 3] = v.w;
  }
  __syncthreads();
#pragma unroll
  for (int p = 0; p < 4; ++p) {
    int n = p * 16 + lr;
    bf16x4 o;
#pragma unroll
    for (int q = 0; q < 4; ++q) o[q] = (bf16)tile[lc + q][n];
    *(bf16x4*)(Wt + (size_t)(roff + n0 + n) * 4096 + k0 + lc) = o;
  }
}

// ---------------- transpose V out of QKV into global: Vt_g[g][d][s] ----------------
__global__ __launch_bounds__(256) void transpose_v(const bf16* __restrict__ QKV,
                                                   bf16* __restrict__ Vt_g) {
  __shared__ bf16 tile[32][33];
  int s0 = blockIdx.x * 32;          // seq tile
  int d0 = blockIdx.y * 32;          // head-dim tile
  int g  = blockIdx.z;               // kv head
  int t = threadIdx.x;
  int r = t >> 5, c = t & 31;
#pragma unroll
  for (int p = 0; p < 4; ++p)
    tile[r + p * 8][c] = QKV[(size_t)(s0 + r + p * 8) * QKVN + 5120 + g * 128 + d0 + c];
  __syncthreads();
#pragma unroll
  for (int p = 0; p < 4; ++p)
    Vt_g[(size_t)(g * 128 + d0 + r + p * 8) * SEQ + s0 + c] = tile[c][r + p * 8];
}

// ---------------- 128x128 GEMM, BK=64, swizzled LDS: A[M,K] @ Bt[N,K]^T -> C[M,ldc] ----------------
template <typename OUT_T>
__global__ __launch_bounds__(256) void gemm_bt(const bf16* __restrict__ A,
                                               const bf16* __restrict__ Bt,
                                               OUT_T* __restrict__ C,
                                               int K, int ldc) {
  __shared__ __align__(16) bf16 Abuf[128 * 64];
  __shared__ __align__(16) bf16 Bbuf[128 * 64];
  int m0 = blockIdx.y * 128, n0 = blockIdx.x * 128;
  int tid = threadIdx.x, w = tid >> 6, lane = tid & 63;
  int wr = w >> 1, wc = w & 1;
  int l15 = lane & 15, l4 = lane >> 4;
  f32x4 acc[4][4] = {};
  const int nk = K >> 6;
  for (int kt = 0; kt < nk; ++kt) {
    int k0 = kt << 6;
#pragma unroll
    for (int p = 0; p < 4; ++p) {
      int c = p * 256 + tid;
      int row = c >> 3, slot = c & 7;
      int ssl = (slot ^ (row & 7)) << 4;   // inverse-swizzled source byte offset
      gload_lds16((const char*)(A + (size_t)(m0 + row) * K + k0) + ssl, (char*)Abuf + c * 16);
      gload_lds16((const char*)(Bt + (size_t)(n0 + row) * K + k0) + ssl, (char*)Bbuf + c * 16);
    }
    __syncthreads();
    bf16x8 af[4][2], bfr[4][2];
#pragma unroll
    for (int m = 0; m < 4; ++m)
#pragma unroll
      for (int kk = 0; kk < 2; ++kk) {
        int row = wr * 64 + m * 16 + l15;
        af[m][kk] = *(const bf16x8*)((const char*)Abuf + row * 128 +
                                     (((kk * 4 + l4) ^ (row & 7)) << 4));
      }
#pragma unroll
    for (int n = 0; n < 4; ++n)
#pragma unroll
      for (int kk = 0; kk < 2; ++kk) {
        int row = wc * 64 + n * 16 + l15;
        bfr[n][kk] = *(const bf16x8*)((const char*)Bbuf + row * 128 +
                                      (((kk * 4 + l4) ^ (row & 7)) << 4));
      }
#pragma unroll
    for (int kk = 0; kk < 2; ++kk)
#pragma unroll
      for (int m = 0; m < 4; ++m)
#pragma unroll
        for (int n = 0; n < 4; ++n)
          acc[m][n] = __builtin_amdgcn_mfma_f32_16x16x32_bf16(af[m][kk], bfr[n][kk],
                                                              acc[m][n], 0, 0, 0);
    __syncthreads();
  }
#pragma unroll
  for (int m = 0; m < 4; ++m)
#pragma unroll
    for (int n = 0; n < 4; ++n)
#pragma unroll
      for (int i = 0; i < 4; ++i) {
        int row = m0 + wr * 64 + m * 16 + l4 * 4 + i;
        int col = n0 + wc * 64 + n * 16 + l15;
        C[(size_t)row * ldc + col] = (OUT_T)acc[m][n][i];
      }
}

// ---------------- flash-style causal GQA attention, v5 ----------------
// 512 blocks x 256 thr (4 waves). Block = kv-head g (bid&7, XCD) x head hi x qb-pair
// (qb_a = pair, qb_b = 31-pair: exactly 33 compute-units/block, perfect balance).
// LDS 72KB -> 2 independent blocks/CU: uncorrelated barrier phases let one block's
// compute hide the other's stage drain (m114 implicit overlap). Sequential per-unit
// compute (v3's proven code path, VGPR ~112). K/V dbuf, stage(t+1) before compute(t),
// T5 setprio on MFMA clusters, T13 defer-max.
__global__ __launch_bounds__(256, 2) void attn_kernel(const bf16* __restrict__ QKV,
                                                      const bf16* __restrict__ Vt_g,
                                                      bf16* __restrict__ attn) {
  __shared__ __align__(16) bf16 Klds[2][64 * 128];   // [ks][d], XOR-swizzled
  __shared__ __align__(16) bf16 Vlds[2][64 * 128];   // [d][ks], XOR-swizzled
  __shared__ __align__(16) bf16 Plds[4 * 16 * 64];   // per-wave [16 q][64 ks], swizzled
  const int bid = blockIdx.x;
  const int g = bid & 7;                 // kv head -> XCD
  const int rest = bid >> 3;             // 0..63
  const int hi = rest & 3;               // head within kv group
  const int pair = rest >> 2;            // 0..15
  const int qb_a = pair, qb_b = 31 - pair;
  const int tid = threadIdx.x, w = tid >> 6, lane = tid & 63;
  const int h = g * 4 + hi;              // this block's q head
  const int l15 = lane & 15, l4 = lane >> 4;
  const int wqA = qb_a * 64 + w * 16;    // wave's q-row base, block A
  const int wqB = qb_b * 64 + w * 16;    // block B
  const int qcol = h * 128;
  const int kcol = 4096 + g * 128;
  const float scale = 0.08838834764831845f;  // 1/sqrt(128)
  const float LOG2E = 1.4426950408889634f;

  const bf16* Vhead = Vt_g + (size_t)g * 128 * SEQ;

  // hoist Q fragments for both q-blocks (16 rows x 128 d each)
  bf16x8 aqA[4], aqB[4];
#pragma unroll
  for (int kc = 0; kc < 4; ++kc) {
    aqA[kc] = *(const bf16x8*)(QKV + (size_t)(wqA + l15) * QKVN + qcol + kc * 32 + l4 * 8);
    aqB[kc] = *(const bf16x8*)(QKV + (size_t)(wqB + l15) * QKVN + qcol + kc * 32 + l4 * 8);
  }

  f32x4 acc_oA[8] = {}, acc_oB[8] = {};
  float mA[4], lA[4], mB[4], lB[4];
#pragma unroll
  for (int i = 0; i < 4; ++i) { mA[i] = -1e30f; lA[i] = 0.f; mB[i] = -1e30f; lB[i] = 0.f; }

  // stage K/V tile at k-offset kb into buffer buf (1024 16B-chunks each, 256 thr x 4)
  auto stageKV = [&](int kb, int buf) {
#pragma unroll
    for (int j = 0; j < 4; ++j) {
      int c = tid + (j << 8);
      int krow = c >> 4, kslot = c & 15;
      gload_lds16((const char*)(QKV + (size_t)(kb + krow) * QKVN + kcol) +
                      ((kslot ^ (krow & 7)) << 4),
                  (char*)Klds[buf] + c * 16);
      int vrow = c >> 3, vslot = c & 7;
      gload_lds16(Vhead + (size_t)vrow * SEQ + kb + ((vslot ^ (vrow & 7)) << 3),
                  (char*)Vlds[buf] + c * 16);
    }
  };

  // per-wave compute of one (head, q-block) unit against tile kb in buffer cur
  auto compute_block = [&](const bf16x8* aq, f32x4* acc_o, float* mrow, float* lrow,
                           int wq0, int kb, int cur) {
    const char* Kbuf = (const char*)Klds[cur];
    const char* Vbuf = (const char*)Vlds[cur];
    f32x4 accs[4] = {};
    __builtin_amdgcn_s_setprio(1);
#pragma unroll
    for (int n = 0; n < 4; ++n) {
      int row_ = n * 16 + l15;
      int sw = (row_ & 7) << 4;
#pragma unroll
      for (int kc = 0; kc < 4; ++kc) {
        bf16x8 bk = *(const bf16x8*)(Kbuf + row_ * 256 + ((kc * 64 + l4 * 16) ^ sw));
        accs[n] = __builtin_amdgcn_mfma_f32_16x16x32_bf16(aq[kc], bk, accs[n], 0, 0, 0);
      }
    }
    __builtin_amdgcn_s_setprio(0);
    bool needmask = (kb + 64 > wq0);
    float s[4][4];
#pragma unroll
    for (int n = 0; n < 4; ++n)
#pragma unroll
      for (int i = 0; i < 4; ++i) {
        float v = accs[n][i] * scale;
        if (needmask) {
          int ks = kb + n * 16 + l15;
          int qr = wq0 + l4 * 4 + i;
          if (ks > qr) v = -1e30f;
        }
        s[n][i] = v;
      }
    // ---- row max (t4) + defer-max decision (T13) ----
    float t4[4];
#pragma unroll
    for (int i = 0; i < 4; ++i) {
      float t = fmaxf(fmaxf(s[0][i], s[1][i]), fmaxf(s[2][i], s[3][i]));
      t = fmaxf(t, __shfl_xor(t, 1));
      t = fmaxf(t, __shfl_xor(t, 2));
      t = fmaxf(t, __shfl_xor(t, 4));
      t = fmaxf(t, __shfl_xor(t, 8));
      t4[i] = t;
    }
    float dm = fmaxf(fmaxf(t4[0] - mrow[0], t4[1] - mrow[1]),
                     fmaxf(t4[2] - mrow[2], t4[3] - mrow[3]));
    if (!__all(dm <= 8.0f)) {
      float fac[4];
#pragma unroll
      for (int i = 0; i < 4; ++i) {
        float mnew = fmaxf(mrow[i], t4[i]);
        fac[i] = exp2f((mrow[i] - mnew) * LOG2E);
        mrow[i] = mnew;
        lrow[i] *= fac[i];
      }
#pragma unroll
      for (int n2 = 0; n2 < 8; ++n2)
#pragma unroll
        for (int i = 0; i < 4; ++i)
          acc_o[n2][i] *= fac[i];
    }
    // ---- P = exp(s - m), row-sum into l ----
    float ps[4][4];
#pragma unroll
    for (int i = 0; i < 4; ++i) {
      float psum = 0.f;
#pragma unroll
      for (int n = 0; n < 4; ++n) {
        float p = exp2f((s[n][i] - mrow[i]) * LOG2E);
        ps[n][i] = p; psum += p;
      }
      psum += __shfl_xor(psum, 1);
      psum += __shfl_xor(psum, 2);
      psum += __shfl_xor(psum, 4);
      psum += __shfl_xor(psum, 8);
      lrow[i] += psum;
    }
    // P write (per-wave region, swizzled) then PV; DS ops are in-order per wave
    char* Pw = (char*)Plds + w * 2048;
#pragma unroll
    for (int n = 0; n < 4; ++n)
#pragma unroll
      for (int i = 0; i < 4; ++i) {
        int r = l4 * 4 + i;
        int b = (r * 128 + (n * 16 + l15) * 2) ^ ((r & 7) << 4);
        *(bf16*)(Pw + b) = (bf16)ps[n][i];
      }
    __builtin_amdgcn_sched_barrier(0);
    asm volatile("" ::: "memory");
    bf16x8 pa[2];
#pragma unroll
    for (int kc = 0; kc < 2; ++kc)
      pa[kc] = *(const bf16x8*)(Pw + (l15 * 128 + ((kc * 64 + l4 * 16) ^ ((l15 & 7) << 4))));
    __builtin_amdgcn_s_setprio(1);
#pragma unroll
    for (int n2 = 0; n2 < 8; ++n2) {
      int row_ = n2 * 16 + l15;
      int sw = (row_ & 7) << 4;
#pragma unroll
      for (int kc = 0; kc < 2; ++kc) {
        bf16x8 bv = *(const bf16x8*)(Vbuf + row_ * 128 + ((kc * 64 + l4 * 16) ^ sw));
        acc_o[n2] = __builtin_amdgcn_mfma_f32_16x16x32_bf16(pa[kc], bv, acc_o[n2], 0, 0, 0);
      }
    }
    __builtin_amdgcn_s_setprio(0);
    asm volatile("" ::: "memory");
  };

  // ---- prologue: stage tile 0; drain ----
  stageKV(0, 0);
  __syncthreads();

  int cur = 0;
  for (int kbi = 0; kbi <= qb_b; ++kbi) {
    int kb = kbi * 64;
    if (kbi < qb_b) stageKV(kb + 64, cur ^ 1);        // issue-early (overlaps compute)
    if (kbi <= qb_a) compute_block(aqA, acc_oA, mA, lA, wqA, kb, cur);
    compute_block(aqB, acc_oB, mB, lB, wqB, kb, cur);
    __syncthreads();                                   // vmcnt(0)+barrier per tile
    cur ^= 1;
  }

  // ---- epilogue ----
#pragma unroll
  for (int n2 = 0; n2 < 8; ++n2)
#pragma unroll
    for (int i = 0; i < 4; ++i) {
      int col = qcol + n2 * 16 + l15;
      attn[(size_t)(wqA + l4 * 4 + i) * 4096 + col] = (bf16)(acc_oA[n2][i] / lA[i]);
      attn[(size_t)(wqB + l4 * 4 + i) * 4096 + col] = (bf16)(acc_oB[n2][i] / lB[i]);
    }
}

extern "C" void kernel_launch(void* const* d_in, const int* in_sizes, int n_in,
                              void* d_out, int out_size, void* d_ws, size_t ws_size,
                              hipStream_t stream) {
  const float* X  = (const float*)d_in[0];
  const float* Wq = (const float*)d_in[1];
  const float* Wk = (const float*)d_in[2];
  const float* Wv = (const float*)d_in[3];
  const float* Wo = (const float*)d_in[4];
  float* out = (float*)d_out;

  const size_t XB_OFF  = 0;
  const size_t WT_OFF  = 16777216;
  const size_t VT_OFF  = WT_OFF + 33554432;       // inside Wt region, past Wo^T
  const size_t QKV_OFF = 16777216 + 50331648;
  if (ws_size < (size_t)92274688) return;

  char* ws = (char*)d_ws;
  bf16* Xb    = (bf16*)(ws + XB_OFF);
  bf16* Wt    = (bf16*)(ws + WT_OFF);
  bf16* Vt_g  = (bf16*)(ws + VT_OFF);
  bf16* QKV   = (bf16*)(ws + QKV_OFF);
  bf16* attnb = Xb;  // reuse after gemm1 consumed Xb

  // 1. cast hidden states
  cast_f32_bf16<<<2048, 256, 0, stream>>>(X, Xb, SEQ * HID);
  // 2. transpose-cast Wq/Wk/Wv into fused [6144][4096] B^T (64x64 vectorized tiles)
  transpose_cast<<<dim3(4096 / 64, 4096 / 64), 256, 0, stream>>>(Wq, Wt, 4096, 0);
  transpose_cast<<<dim3(1024 / 64, 4096 / 64), 256, 0, stream>>>(Wk, Wt, 1024, 4096);
  transpose_cast<<<dim3(1024 / 64, 4096 / 64), 256, 0, stream>>>(Wv, Wt, 1024, 5120);
  // 3. fused QKV projection: [2048,4096] @ [4096,6144]
  gemm_bt<bf16><<<dim3(QKVN / 128, SEQ / 128), 256, 0, stream>>>(Xb, Wt, QKV, HID, QKVN);
  // 4. transpose-cast Wo (reuses Wt space) + transpose V into global [g][d][s]
  transpose_cast<<<dim3(4096 / 64, 4096 / 64), 256, 0, stream>>>(Wo, Wt, 4096, 0);
  transpose_v<<<dim3(SEQ / 32, 4, 8), 256, 0, stream>>>(QKV, Vt_g);
  // 5. causal GQA flash attention v5 (512 blocks x 4 waves, 2 blocks/CU)
  attn_kernel<<<512, 256, 0, stream>>>(QKV, Vt_g, attnb);
  // 6. output projection -> f32 out: [2048,4096] @ [4096,4096]
  gemm_bt<float><<<dim3(4096 / 128, SEQ / 128), 256, 0, stream>>>(attnb, Wt, out, HID, 4096);
}

// Round 8
// 369.821 us; speedup vs baseline: 1.0555x; 1.0269x over previous
//
#include <hip/hip_runtime.h>
#include <hip/hip_bf16.h>

typedef __bf16 bf16;
typedef __bf16 bf16x4 __attribute__((ext_vector_type(4)));
typedef __bf16 bf16x8 __attribute__((ext_vector_type(8)));
typedef float  f32x4  __attribute__((ext_vector_type(4)));
typedef float  f32x16 __attribute__((ext_vector_type(16)));
typedef unsigned u32x4 __attribute__((ext_vector_type(4)));

#define SEQ  2048
#define HID  4096
#define QKVN 6144   // 4096 Q + 1024 K + 1024 V

__device__ __forceinline__ void gload_lds16(const void* g, void* l) {
  __builtin_amdgcn_global_load_lds(
      (const __attribute__((address_space(1))) void*)g,
      (__attribute__((address_space(3))) void*)l, 16, 0, 0);
}

// v_cvt_pk_bf16_f32: lo -> D[15:0], hi -> D[31:16]  (no builtin on gfx950, m240)
__device__ __forceinline__ unsigned cvtpk(float lo, float hi) {
  unsigned r;
  asm("v_cvt_pk_bf16_f32 %0, %1, %2" : "=v"(r) : "v"(lo), "v"(hi));
  return r;
}
// v_permlane32_swap_b32: exchanges dst.hi(32 lanes) with src.lo — guide T12 recipe order
__device__ __forceinline__ void plswap(unsigned& a, unsigned& b) {
  asm("v_permlane32_swap_b32 %0, %1" : "+v"(a), "+v"(b));
}

// ---------------- cast f32 -> bf16 (vectorized) ----------------
__global__ __launch_bounds__(256) void cast_f32_bf16(const float* __restrict__ in,
                                                     bf16* __restrict__ out, int n) {
  int i = (blockIdx.x * 256 + threadIdx.x) * 4;
  int stride = gridDim.x * 256 * 4;
  for (; i < n; i += stride) {
    float4 v = *(const float4*)(in + i);
    bf16x4 o;
    o[0] = (bf16)v.x; o[1] = (bf16)v.y; o[2] = (bf16)v.z; o[3] = (bf16)v.w;
    *(bf16x4*)(out + i) = o;
  }
}

// ---------------- tiled transpose + cast: W[4096][N] f32 -> Wt[roff+N][4096] bf16 ----------------
__global__ __launch_bounds__(256) void transpose_cast(const float* __restrict__ W,
                                                      bf16* __restrict__ Wt,
                                                      int N, int roff) {
  __shared__ float tile[64][65];
  int k0 = blockIdx.y * 64;
  int n0 = blockIdx.x * 64;
  int t = threadIdx.x;
  int lr = t >> 4;            // 0..15
  int lc = (t & 15) * 4;      // 0,4,...,60
#pragma unroll
  for (int p = 0; p < 4; ++p) {
    int row = p * 16 + lr;
    float4 v = *(const float4*)(W + (size_t)(k0 + row) * N + n0 + lc);
    tile[row][lc] = v.x; tile[row][lc + 1] = v.y;
    tile[row][lc + 2] = v.z; tile[row][lc + 3] = v.w;
  }
  __syncthreads();
#pragma unroll
  for (int p = 0; p < 4; ++p) {
    int n = p * 16 + lr;
    bf16x4 o;
#pragma unroll
    for (int q = 0; q < 4; ++q) o[q] = (bf16)tile[lc + q][n];
    *(bf16x4*)(Wt + (size_t)(roff + n0 + n) * 4096 + k0 + lc) = o;
  }
}

// ---------------- transpose V out of QKV into global: Vt_g[g][d][s] ----------------
__global__ __launch_bounds__(256) void transpose_v(const bf16* __restrict__ QKV,
                                                   bf16* __restrict__ Vt_g) {
  __shared__ bf16 tile[32][33];
  int s0 = blockIdx.x * 32;
  int d0 = blockIdx.y * 32;
  int g  = blockIdx.z;
  int t = threadIdx.x;
  int r = t >> 5, c = t & 31;
#pragma unroll
  for (int p = 0; p < 4; ++p)
    tile[r + p * 8][c] = QKV[(size_t)(s0 + r + p * 8) * QKVN + 5120 + g * 128 + d0 + c];
  __syncthreads();
#pragma unroll
  for (int p = 0; p < 4; ++p)
    Vt_g[(size_t)(g * 128 + d0 + r + p * 8) * SEQ + s0 + c] = tile[c][r + p * 8];
}

// ---------------- 128x128 GEMM, BK=64, swizzled LDS (frozen since r5) ----------------
template <typename OUT_T>
__global__ __launch_bounds__(256) void gemm_bt(const bf16* __restrict__ A,
                                               const bf16* __restrict__ Bt,
                                               OUT_T* __restrict__ C,
                                               int K, int ldc) {
  __shared__ __align__(16) bf16 Abuf[128 * 64];
  __shared__ __align__(16) bf16 Bbuf[128 * 64];
  int m0 = blockIdx.y * 128, n0 = blockIdx.x * 128;
  int tid = threadIdx.x, w = tid >> 6, lane = tid & 63;
  int wr = w >> 1, wc = w & 1;
  int l15 = lane & 15, l4 = lane >> 4;
  f32x4 acc[4][4] = {};
  const int nk = K >> 6;
  for (int kt = 0; kt < nk; ++kt) {
    int k0 = kt << 6;
#pragma unroll
    for (int p = 0; p < 4; ++p) {
      int c = p * 256 + tid;
      int row = c >> 3, slot = c & 7;
      int ssl = (slot ^ (row & 7)) << 4;
      gload_lds16((const char*)(A + (size_t)(m0 + row) * K + k0) + ssl, (char*)Abuf + c * 16);
      gload_lds16((const char*)(Bt + (size_t)(n0 + row) * K + k0) + ssl, (char*)Bbuf + c * 16);
    }
    __syncthreads();
    bf16x8 af[4][2], bfr[4][2];
#pragma unroll
    for (int m = 0; m < 4; ++m)
#pragma unroll
      for (int kk = 0; kk < 2; ++kk) {
        int row = wr * 64 + m * 16 + l15;
        af[m][kk] = *(const bf16x8*)((const char*)Abuf + row * 128 +
                                     (((kk * 4 + l4) ^ (row & 7)) << 4));
      }
#pragma unroll
    for (int n = 0; n < 4; ++n)
#pragma unroll
      for (int kk = 0; kk < 2; ++kk) {
        int row = wc * 64 + n * 16 + l15;
        bfr[n][kk] = *(const bf16x8*)((const char*)Bbuf + row * 128 +
                                      (((kk * 4 + l4) ^ (row & 7)) << 4));
      }
#pragma unroll
    for (int kk = 0; kk < 2; ++kk)
#pragma unroll
      for (int m = 0; m < 4; ++m)
#pragma unroll
        for (int n = 0; n < 4; ++n)
          acc[m][n] = __builtin_amdgcn_mfma_f32_16x16x32_bf16(af[m][kk], bfr[n][kk],
                                                              acc[m][n], 0, 0, 0);
    __syncthreads();
  }
#pragma unroll
  for (int m = 0; m < 4; ++m)
#pragma unroll
    for (int n = 0; n < 4; ++n)
#pragma unroll
      for (int i = 0; i < 4; ++i) {
        int row = m0 + wr * 64 + m * 16 + l4 * 4 + i;
        int col = n0 + wc * 64 + n * 16 + l15;
        C[(size_t)row * ldc + col] = (OUT_T)acc[m][n][i];
      }
}

// ---------------- attention v6: 32x32 swapped-operand, in-register softmax ----------------
// 512 blocks x 256 thr (4 waves). Block = (g = bid&7 -> XCD, head, qb-pair).
// Waves 0,1 = halves of q-block qb_b (always active); waves 2,3 = halves of qb_a
// (active while kbi <= qb_a). 66 32-row wave-units per block = perfect balance.
// Swapped QK^T (mfma(K,Q)) -> S^T: q = lane&31, k in-register; softmax per-lane scalar
// (m,l) + ONE shfl_xor(32). P^T -> PV b-frags via cvt_pk + permlane32_swap (T12, no LDS).
// K: [64][128] 16-slot XOR swizzle; V: d-pair-packed [64][256B] 16-slot swizzle.
// LDS 64KB -> 2 blocks/CU. T13 defer-max (thr 8). setprio on MFMA clusters.
__global__ __launch_bounds__(256, 2) void attn_kernel(const bf16* __restrict__ QKV,
                                                      const bf16* __restrict__ Vt_g,
                                                      bf16* __restrict__ attn) {
  __shared__ __align__(16) bf16 Klds[2][64 * 128];
  __shared__ __align__(16) bf16 Vlds[2][64 * 128];
  const int bid = blockIdx.x;
  const int g = bid & 7;
  const int rest = bid >> 3;
  const int hi = rest & 3;
  const int pair = rest >> 2;            // 0..15
  const int qb_a = pair, qb_b = 31 - pair;
  const int tid = threadIdx.x, w = tid >> 6, lane = tid & 63;
  const int l31 = lane & 31, hh = lane >> 5;
  const int head = g * 4 + hi;
  const bool isB = (w < 2);
  const int myqb = isB ? qb_b : qb_a;
  const int unit_q0 = myqb * 64 + (w & 1) * 32;
  const int qcol = head * 128;
  const int kcol = 4096 + g * 128;
  const float scale = 0.08838834764831845f;  // 1/sqrt(128)
  const float LOG2E = 1.4426950408889634f;

  const bf16* Vhead = Vt_g + (size_t)g * 128 * SEQ;

  // hoist Q as 8 b-frags: lane supplies col q=l31, elems = d (hh*8+j within 16-d block)
  bf16x8 qf[8];
#pragma unroll
  for (int db = 0; db < 8; ++db)
    qf[db] = *(const bf16x8*)(QKV + (size_t)(unit_q0 + l31) * QKVN + qcol +
                              db * 16 + hh * 8);

  f32x16 acc_o[4] = {};     // O^T per d-tile: col=q(l31), row=d-offset
  float m_run = -1e30f, l_run = 0.f;

  // stage K (1024 chunks) + V (1024 chunks), linear LDS dest, inverse-swizzled source
  auto stageKV = [&](int kb, int buf) {
#pragma unroll
    for (int j = 0; j < 4; ++j) {
      int c = tid + (j << 8);
      int row = c >> 4, s = c & 15;
      int sl = s ^ (row & 15);
      gload_lds16((const char*)(QKV + (size_t)(kb + row) * QKVN + kcol) + (sl << 4),
                  (char*)Klds[buf] + (c << 4));
      int d = row * 2 + (sl >> 3);
      int ko = (sl & 7) << 3;
      gload_lds16(Vhead + (size_t)d * SEQ + kb + ko, (char*)Vlds[buf] + (c << 4));
    }
  };

  auto compute_unit = [&](int kb, int cur) {
    const char* Kb = (const char*)Klds[cur];
    const char* Vb = (const char*)Vlds[cur];
    // ---- QK^T swapped: S^T[k][q], two 32-k tiles ----
    f32x16 s0 = {}, s1 = {};
    __builtin_amdgcn_s_setprio(1);
#pragma unroll
    for (int db = 0; db < 8; ++db) {
      int slot = (db * 2 + hh) ^ (l31 & 15);
      bf16x8 k0 = *(const bf16x8*)(Kb + l31 * 256 + slot * 16);
      bf16x8 k1 = *(const bf16x8*)(Kb + (32 + l31) * 256 + slot * 16);
      s0 = __builtin_amdgcn_mfma_f32_32x32x16_bf16(k0, qf[db], s0, 0, 0, 0);
      s1 = __builtin_amdgcn_mfma_f32_32x32x16_bf16(k1, qf[db], s1, 0, 0, 0);
    }
    __builtin_amdgcn_s_setprio(0);
    // ---- scale + causal mask (k = kb + kt*32 + (r&3)+8*(r>>2)+4*hh; q = unit_q0+l31) ----
    float p0[16], p1[16];
    const bool needmask = (kb + 64 > unit_q0);
    const int qg = unit_q0 + l31;
#pragma unroll
    for (int r = 0; r < 16; ++r) {
      float v0 = s0[r] * scale, v1 = s1[r] * scale;
      if (needmask) {
        int krow = (r & 3) + 8 * (r >> 2) + 4 * hh;
        if (kb + krow > qg)      v0 = -1e30f;
        if (kb + 32 + krow > qg) v1 = -1e30f;
      }
      p0[r] = v0; p1[r] = v1;
    }
    // ---- per-lane row max (+ partner half) ----
    float t = fmaxf(p0[0], p1[0]);
#pragma unroll
    for (int r = 1; r < 16; ++r) t = fmaxf(t, fmaxf(p0[r], p1[r]));
    t = fmaxf(t, __shfl_xor(t, 32));
    // ---- T13 defer-max ----
    if (!__all(t - m_run <= 8.0f)) {
      float mnew = fmaxf(m_run, t);
      float fac = exp2f((m_run - mnew) * LOG2E);
      m_run = mnew;
      l_run *= fac;
#pragma unroll
      for (int dt = 0; dt < 4; ++dt)
#pragma unroll
        for (int r = 0; r < 16; ++r) acc_o[dt][r] *= fac;
    }
    // ---- P = exp2((s-m)*log2e), row-sum ----
    float psum = 0.f;
#pragma unroll
    for (int r = 0; r < 16; ++r) {
      p0[r] = exp2f((p0[r] - m_run) * LOG2E); psum += p0[r];
      p1[r] = exp2f((p1[r] - m_run) * LOG2E); psum += p1[r];
    }
    psum += __shfl_xor(psum, 32);
    l_run += psum;
    // ---- build PV b-frags in-register: T12 cvt_pk + permlane32_swap ----
    bf16x8 paf[4];
#pragma unroll
    for (int kstep = 0; kstep < 4; ++kstep) {
      const float* p = (kstep < 2) ? p0 : p1;
      const int base = (kstep & 1) * 8;
      unsigned a0 = cvtpk(p[base + 0], p[base + 1]);
      unsigned b0 = cvtpk(p[base + 4], p[base + 5]);
      plswap(a0, b0);                    // a0 = (j0,j1) word, b0 = (j4,j5) word
      unsigned a1 = cvtpk(p[base + 2], p[base + 3]);
      unsigned b1 = cvtpk(p[base + 6], p[base + 7]);
      plswap(a1, b1);                    // a1 = (j2,j3), b1 = (j6,j7)
      u32x4 pw; pw[0] = a0; pw[1] = a1; pw[2] = b0; pw[3] = b1;
      paf[kstep] = __builtin_bit_cast(bf16x8, pw);
    }
    // ---- PV: O^T[d][q] += V^T[d][k] * P^T[k][q] ----
    __builtin_amdgcn_s_setprio(1);
#pragma unroll
    for (int dt = 0; dt < 4; ++dt) {
      int vrow = dt * 16 + (l31 >> 1);
#pragma unroll
      for (int kstep = 0; kstep < 4; ++kstep) {
        int slot = ((l31 & 1) * 8 + kstep * 2 + hh) ^ (vrow & 15);
        bf16x8 vf = *(const bf16x8*)(Vb + vrow * 256 + slot * 16);
        acc_o[dt] = __builtin_amdgcn_mfma_f32_32x32x16_bf16(vf, paf[kstep], acc_o[dt], 0, 0, 0);
      }
    }
    __builtin_amdgcn_s_setprio(0);
  };

  // ---- prologue ----
  stageKV(0, 0);
  __syncthreads();

  int cur = 0;
  for (int kbi = 0; kbi <= qb_b; ++kbi) {
    int kb = kbi * 64;
    if (kbi < qb_b) stageKV(kb + 64, cur ^ 1);   // issue-early, overlaps compute
    if (isB || kbi <= qb_a) compute_unit(kb, cur);
    __syncthreads();
    cur ^= 1;
  }

  // ---- epilogue: attn[q][qcol + d] = O^T[d][q] / l ----
  float inv_l = 1.0f / l_run;
  bf16* orow = attn + (size_t)(unit_q0 + l31) * 4096 + qcol;
#pragma unroll
  for (int dt = 0; dt < 4; ++dt)
#pragma unroll
    for (int r = 0; r < 16; ++r) {
      int d = dt * 32 + (r & 3) + 8 * (r >> 2) + 4 * hh;
      orow[d] = (bf16)(acc_o[dt][r] * inv_l);
    }
}

extern "C" void kernel_launch(void* const* d_in, const int* in_sizes, int n_in,
                              void* d_out, int out_size, void* d_ws, size_t ws_size,
                              hipStream_t stream) {
  const float* X  = (const float*)d_in[0];
  const float* Wq = (const float*)d_in[1];
  const float* Wk = (const float*)d_in[2];
  const float* Wv = (const float*)d_in[3];
  const float* Wo = (const float*)d_in[4];
  float* out = (float*)d_out;

  const size_t XB_OFF  = 0;
  const size_t WT_OFF  = 16777216;
  const size_t VT_OFF  = WT_OFF + 33554432;
  const size_t QKV_OFF = 16777216 + 50331648;
  if (ws_size < (size_t)92274688) return;

  char* ws = (char*)d_ws;
  bf16* Xb    = (bf16*)(ws + XB_OFF);
  bf16* Wt    = (bf16*)(ws + WT_OFF);
  bf16* Vt_g  = (bf16*)(ws + VT_OFF);
  bf16* QKV   = (bf16*)(ws + QKV_OFF);
  bf16* attnb = Xb;

  cast_f32_bf16<<<2048, 256, 0, stream>>>(X, Xb, SEQ * HID);
  transpose_cast<<<dim3(4096 / 64, 4096 / 64), 256, 0, stream>>>(Wq, Wt, 4096, 0);
  transpose_cast<<<dim3(1024 / 64, 4096 / 64), 256, 0, stream>>>(Wk, Wt, 1024, 4096);
  transpose_cast<<<dim3(1024 / 64, 4096 / 64), 256, 0, stream>>>(Wv, Wt, 1024, 5120);
  gemm_bt<bf16><<<dim3(QKVN / 128, SEQ / 128), 256, 0, stream>>>(Xb, Wt, QKV, HID, QKVN);
  transpose_cast<<<dim3(4096 / 64, 4096 / 64), 256, 0, stream>>>(Wo, Wt, 4096, 0);
  transpose_v<<<dim3(SEQ / 32, 4, 8), 256, 0, stream>>>(QKV, Vt_g);
  // attention v6: 32x32 swapped-operand in-register softmax
  attn_kernel<<<512, 256, 0, stream>>>(QKV, Vt_g, attnb);
  gemm_bt<float><<<dim3(4096 / 128, SEQ / 128), 256, 0, stream>>>(attnb, Wt, out, HID, 4096);
}